// Round 1
// baseline (186.151 us; speedup 1.0000x reference)
//
#include <hip/hip_runtime.h>
#include <hip/hip_bf16.h>

#define BATCH 2048
#define NTEACH 64

// ---------------- sort: bucket samples by teacher ----------------
__global__ __launch_bounds__(256) void sort_kernel(const int* __restrict__ tidx,
                                                   int* __restrict__ offsets,
                                                   int* __restrict__ order) {
    __shared__ int cnt[NTEACH];
    __shared__ int offs[NTEACH + 1];
    __shared__ int cur[NTEACH];
    int tid = threadIdx.x;
    if (tid < NTEACH) cnt[tid] = 0;
    __syncthreads();
    for (int i = tid; i < BATCH; i += 256) atomicAdd(&cnt[tidx[i]], 1);
    __syncthreads();
    if (tid == 0) {
        int a = 0;
        for (int t = 0; t < NTEACH; ++t) { offs[t] = a; a += cnt[t]; }
        offs[NTEACH] = a;
    }
    __syncthreads();
    if (tid < NTEACH) cur[tid] = offs[tid];
    if (tid < NTEACH + 1) offsets[tid] = offs[tid];
    __syncthreads();
    for (int i = tid; i < BATCH; i += 256) {
        int p = atomicAdd(&cur[tidx[i]], 1);
        order[p] = i;
    }
}

// ---------------- generic layer: y[sorted] = act(W[t] @ x + b[t]) ----------------
// Block: (out-tile o0 = blockIdx.x*OT, teacher t = blockIdx.y), 256 threads.
// Thread tile: 4 outputs x 2 samples. LDS: W^T tile (pad +4 -> aligned b128
// reads, 2-way-free bank pattern), x tile (pad +1, conflict-free).
template <int K, int KC, int OUT, int OT, bool GATHER, bool IS_ELU>
__global__ __launch_bounds__(256) void layer_kernel(const float* __restrict__ xin,
                                                    const float* __restrict__ W,
                                                    const float* __restrict__ Bv,
                                                    const int* __restrict__ offsets,
                                                    const int* __restrict__ order,
                                                    float* __restrict__ y) {
    __shared__ float wT[KC][OT + 4];
    __shared__ float xs[32][KC + 1];
    __shared__ int smp[32];

    const int t = blockIdx.y;
    const int o0 = blockIdx.x * OT;
    const int start = offsets[t];
    const int end = offsets[t + 1];
    const int tid = threadIdx.x;
    const int ti = tid & 15;   // output sub-tile
    const int tj = tid >> 4;   // sample sub-tile

    for (int s0 = start; s0 < end; s0 += 32) {
        if (tid < 32) {
            int sg = s0 + tid;
            smp[tid] = (sg < end) ? (GATHER ? order[sg] : sg) : -1;
        }
        float acc[2][4];
#pragma unroll
        for (int a = 0; a < 2; ++a)
#pragma unroll
            for (int b = 0; b < 4; ++b) acc[a][b] = 0.f;

        for (int k0 = 0; k0 < K; k0 += KC) {
            __syncthreads();
            // stage W^T tile (coalesced along K)
#pragma unroll
            for (int idx = tid; idx < OT * KC; idx += 256) {
                int r = idx / KC, c = idx % KC;
                wT[c][r] = W[(size_t)(t * OUT + o0 + r) * K + k0 + c];
            }
            // stage x tile
#pragma unroll
            for (int idx = tid; idx < 32 * KC; idx += 256) {
                int s = idx / KC, c = idx % KC;
                int sm = smp[s];
                xs[s][c] = (sm >= 0) ? xin[(size_t)sm * K + k0 + c] : 0.f;
            }
            __syncthreads();
#pragma unroll
            for (int k = 0; k < KC; ++k) {
                float4 wv = *reinterpret_cast<const float4*>(&wT[k][4 * ti]);
                float xa = xs[2 * tj][k];
                float xb = xs[2 * tj + 1][k];
                acc[0][0] += wv.x * xa; acc[0][1] += wv.y * xa;
                acc[0][2] += wv.z * xa; acc[0][3] += wv.w * xa;
                acc[1][0] += wv.x * xb; acc[1][1] += wv.y * xb;
                acc[1][2] += wv.z * xb; acc[1][3] += wv.w * xb;
            }
        }
        // epilogue: bias + activation, store in sorted order
#pragma unroll
        for (int jj = 0; jj < 2; ++jj) {
            int sg = s0 + 2 * tj + jj;
            if (sg < end) {
#pragma unroll
                for (int ii = 0; ii < 4; ++ii) {
                    int o = o0 + 4 * ti + ii;
                    float v = acc[jj][ii] + Bv[t * OUT + o];
                    if (IS_ELU) v = (v > 0.f) ? v : expm1f(v);
                    y[(size_t)sg * OUT + o] = v;
                }
            }
        }
    }
}

// ---------------- final layer: out[orig] = tanh(W6[t] @ h2 + b6[t]) ----------------
__global__ __launch_bounds__(256) void final_kernel(const float* __restrict__ h2,
                                                    const float* __restrict__ W,
                                                    const float* __restrict__ Bv,
                                                    const int* __restrict__ offsets,
                                                    const int* __restrict__ order,
                                                    float* __restrict__ out) {
    const int t = blockIdx.x;
    const int start = offsets[t];
    const int end = offsets[t + 1];
    const int n = (end - start) * 12;
    for (int idx = threadIdx.x; idx < n; idx += 256) {
        int sl = idx / 12;
        int o = idx - sl * 12;
        int s = start + sl;
        const float4* wr = reinterpret_cast<const float4*>(&W[(size_t)(t * 12 + o) * 128]);
        const float4* xr = reinterpret_cast<const float4*>(&h2[(size_t)s * 128]);
        float acc = 0.f;
#pragma unroll 8
        for (int k = 0; k < 32; ++k) {
            float4 a = wr[k];
            float4 b = xr[k];
            acc += a.x * b.x + a.y * b.y + a.z * b.z + a.w * b.w;
        }
        out[(size_t)order[s] * 12 + o] = tanhf(acc + Bv[t * 12 + o]);
    }
}

extern "C" void kernel_launch(void* const* d_in, const int* in_sizes, int n_in,
                              void* d_out, int out_size, void* d_ws, size_t ws_size,
                              hipStream_t stream) {
    const float* obs = (const float*)d_in[0];
    const int* tidx  = (const int*)d_in[1];
    const float* w0  = (const float*)d_in[2];
    const float* b0  = (const float*)d_in[3];
    const float* w2  = (const float*)d_in[4];
    const float* b2  = (const float*)d_in[5];
    const float* w4  = (const float*)d_in[6];
    const float* b4  = (const float*)d_in[7];
    const float* w6  = (const float*)d_in[8];
    const float* b6  = (const float*)d_in[9];
    float* out = (float*)d_out;

    char* ws = (char*)d_ws;
    int* offsets = (int*)ws;                    // 65 ints
    int* order   = (int*)(ws + 1024);           // 2048 ints
    float* h0 = (float*)(ws + 16384);           // 2048*512
    float* h1 = h0 + (size_t)BATCH * 512;       // 2048*256
    float* h2 = h1 + (size_t)BATCH * 256;       // 2048*128

    sort_kernel<<<1, 256, 0, stream>>>(tidx, offsets, order);
    layer_kernel<48, 48, 512, 64, true, true>
        <<<dim3(8, NTEACH), 256, 0, stream>>>(obs, w0, b0, offsets, order, h0);
    layer_kernel<512, 64, 256, 64, false, true>
        <<<dim3(4, NTEACH), 256, 0, stream>>>(h0, w2, b2, offsets, order, h1);
    layer_kernel<256, 64, 128, 64, false, true>
        <<<dim3(2, NTEACH), 256, 0, stream>>>(h1, w4, b4, offsets, order, h2);
    final_kernel<<<NTEACH, 256, 0, stream>>>(h2, w6, b6, offsets, order, out);
}

// Round 2
// 100.987 us; speedup vs baseline: 1.8433x; 1.8433x over previous
//
#include <hip/hip_runtime.h>

#define BATCH 2048
#define NTEACH 64

// ---------------- sort: bucket samples by teacher ----------------
__global__ __launch_bounds__(256) void sort_kernel(const int* __restrict__ tidx,
                                                   int* __restrict__ offsets,
                                                   int* __restrict__ order) {
    __shared__ int cnt[NTEACH];
    __shared__ int offs[NTEACH + 1];
    __shared__ int cur[NTEACH];
    int tid = threadIdx.x;
    if (tid < NTEACH) cnt[tid] = 0;
    __syncthreads();
    for (int i = tid; i < BATCH; i += 256) atomicAdd(&cnt[tidx[i]], 1);
    __syncthreads();
    if (tid == 0) {
        int a = 0;
        for (int t = 0; t < NTEACH; ++t) { offs[t] = a; a += cnt[t]; }
        offs[NTEACH] = a;
    }
    __syncthreads();
    if (tid < NTEACH) cur[tid] = offs[tid];
    if (tid < NTEACH + 1) offsets[tid] = offs[tid];
    __syncthreads();
    for (int i = tid; i < BATCH; i += 256) {
        int p = atomicAdd(&cur[tidx[i]], 1);
        order[p] = i;
    }
}

// ---------------- layer: y[sorted] = act(W[t] @ x + b[t]) ----------------
// Block = (out-tile OT, teacher). 256 threads = OT4 x 8 x KS:
//   ti (output quad), tj (sample quad), kq (K-slice). Each thread: 4x4 reg tile.
// K-slices reduced through LDS at the end. Reg-staged prefetch of next K-chunk.
// wT XOR-swizzled (conflict-free b128 reads), xs XOR-swizzled (<=2-way, free).
template <int K, int KC, int OUT, int OT, int KS, bool GATHER, bool IS_ELU>
__global__ __launch_bounds__(256) void layer_kernel(const float* __restrict__ xin,
                                                    const float* __restrict__ W,
                                                    const float* __restrict__ Bv,
                                                    const int* __restrict__ offsets,
                                                    const int* __restrict__ order,
                                                    float* __restrict__ y) {
    constexpr int OT4 = OT / 4;
    constexpr int KC4 = KC / 4;
    constexpr int KPW = KC / KS;        // k's per K-slice per chunk
    constexpr int KPW4 = KPW / 4;
    constexpr int G = OT4 * 8;          // threads per K-slice group
    constexpr int NC = K / KC;          // chunks
    constexpr int WN = OT * KC4;        // float4s in W tile
    constexpr int XN = 32 * KC4;        // float4s in x tile
    constexpr int WTRIP = (WN + 255) / 256;
    constexpr int XTRIP = (XN + 255) / 256;
    static_assert(G * KS == 256, "thread mapping");
    static_assert(KPW4 * 4 == KPW, "K-slice must be multiple of 4");
    static_assert(K % KC == 0 && OUT % OT == 0, "tiling");

    __shared__ float wT[KC * OT];                 // [k][swizzled o]
    __shared__ float xs[32 * KC];                 // [s][swizzled k4]
    __shared__ float red[(KS - 1) * G * 20];      // stride 20 floats: 16B-aligned, bank-spread

    const int t = blockIdx.y;
    const int o0 = blockIdx.x * OT;
    const int start = offsets[t];
    const int end = offsets[t + 1];
    const int tid = threadIdx.x;
    const int ti = tid % OT4;
    const int tj = (tid / OT4) & 7;
    const int kq = tid / G;
    const int gid = tid % G;
    const int swz = tj & 3;

    const float* Wt = W + ((size_t)t * OUT + o0) * K;

    for (int s0 = start; s0 < end; s0 += 32) {
        float4 acc[4];
#pragma unroll
        for (int j = 0; j < 4; ++j) acc[j] = float4{0.f, 0.f, 0.f, 0.f};

        float4 wreg[WTRIP], xreg[XTRIP];
        // ---- prefetch chunk 0 into registers ----
#pragma unroll
        for (int tr = 0; tr < WTRIP; ++tr) {
            int idx = tid + tr * 256;
            if (idx < WN) {
                int o = idx / KC4, k4 = idx % KC4;
                wreg[tr] = *reinterpret_cast<const float4*>(&Wt[(size_t)o * K + 4 * k4]);
            }
        }
#pragma unroll
        for (int tr = 0; tr < XTRIP; ++tr) {
            int idx = tid + tr * 256;
            if (idx < XN) {
                int s = idx / KC4, k4 = idx % KC4;
                int sg = s0 + s;
                if (sg < end) {
                    int sm = GATHER ? order[sg] : sg;
                    xreg[tr] = *reinterpret_cast<const float4*>(&xin[(size_t)sm * K + 4 * k4]);
                } else {
                    xreg[tr] = float4{0.f, 0.f, 0.f, 0.f};
                }
            }
        }

        for (int c = 0; c < NC; ++c) {
            __syncthreads();   // previous chunk's compute done; LDS free
            // ---- write staged registers into LDS (swizzled) ----
#pragma unroll
            for (int tr = 0; tr < WTRIP; ++tr) {
                int idx = tid + tr * 256;
                if (idx < WN) {
                    int o = idx / KC4, k4 = idx % KC4;
                    int oq = o >> 2, ob = o & 3;
                    const float* wf = reinterpret_cast<const float*>(&wreg[tr]);
#pragma unroll
                    for (int m = 0; m < 4; ++m) {
                        int k = 4 * k4 + m;
                        wT[k * OT + 4 * (oq ^ (k & (OT4 - 1))) + ob] = wf[m];
                    }
                }
            }
#pragma unroll
            for (int tr = 0; tr < XTRIP; ++tr) {
                int idx = tid + tr * 256;
                if (idx < XN) {
                    int s = idx / KC4, k4 = idx % KC4;
                    *reinterpret_cast<float4*>(&xs[s * KC + 4 * (k4 ^ ((s >> 2) & 3))]) = xreg[tr];
                }
            }
            // ---- prefetch chunk c+1 (hides under compute below) ----
            if (c + 1 < NC) {
                int k0n = (c + 1) * KC;
#pragma unroll
                for (int tr = 0; tr < WTRIP; ++tr) {
                    int idx = tid + tr * 256;
                    if (idx < WN) {
                        int o = idx / KC4, k4 = idx % KC4;
                        wreg[tr] = *reinterpret_cast<const float4*>(&Wt[(size_t)o * K + k0n + 4 * k4]);
                    }
                }
#pragma unroll
                for (int tr = 0; tr < XTRIP; ++tr) {
                    int idx = tid + tr * 256;
                    if (idx < XN) {
                        int s = idx / KC4, k4 = idx % KC4;
                        int sg = s0 + s;
                        if (sg < end) {
                            int sm = GATHER ? order[sg] : sg;
                            xreg[tr] = *reinterpret_cast<const float4*>(&xin[(size_t)sm * K + k0n + 4 * k4]);
                        } else {
                            xreg[tr] = float4{0.f, 0.f, 0.f, 0.f};
                        }
                    }
                }
            }
            __syncthreads();   // LDS tiles ready
            // ---- compute this K-slice ----
#pragma unroll
            for (int kk4 = 0; kk4 < KPW4; ++kk4) {
                float4 xv[4];
#pragma unroll
                for (int j = 0; j < 4; ++j)
                    xv[j] = *reinterpret_cast<const float4*>(
                        &xs[(4 * tj + j) * KC + 4 * ((kq * KPW4 + kk4) ^ swz)]);
#pragma unroll
                for (int m = 0; m < 4; ++m) {
                    int k = kq * KPW + kk4 * 4 + m;
                    float4 wv = *reinterpret_cast<const float4*>(
                        &wT[k * OT + 4 * (ti ^ (k & (OT4 - 1)))]);
#pragma unroll
                    for (int j = 0; j < 4; ++j) {
                        float xm = reinterpret_cast<const float*>(&xv[j])[m];
                        acc[j].x += wv.x * xm;
                        acc[j].y += wv.y * xm;
                        acc[j].z += wv.z * xm;
                        acc[j].w += wv.w * xm;
                    }
                }
            }
        }
        // ---- cross-K-slice reduction via LDS ----
        __syncthreads();
        if (kq > 0) {
#pragma unroll
            for (int j = 0; j < 4; ++j)
                *reinterpret_cast<float4*>(&red[((kq - 1) * G + gid) * 20 + 4 * j]) = acc[j];
        }
        __syncthreads();
        if (kq == 0) {
#pragma unroll
            for (int q = 0; q < KS - 1; ++q)
#pragma unroll
                for (int j = 0; j < 4; ++j) {
                    float4 r = *reinterpret_cast<const float4*>(&red[(q * G + gid) * 20 + 4 * j]);
                    acc[j].x += r.x; acc[j].y += r.y; acc[j].z += r.z; acc[j].w += r.w;
                }
            float4 bv = *reinterpret_cast<const float4*>(&Bv[t * OUT + o0 + 4 * ti]);
#pragma unroll
            for (int j = 0; j < 4; ++j) {
                int sg = s0 + 4 * tj + j;
                if (sg < end) {
                    float4 v;
                    v.x = acc[j].x + bv.x;
                    v.y = acc[j].y + bv.y;
                    v.z = acc[j].z + bv.z;
                    v.w = acc[j].w + bv.w;
                    if (IS_ELU) {
                        v.x = v.x > 0.f ? v.x : expm1f(v.x);
                        v.y = v.y > 0.f ? v.y : expm1f(v.y);
                        v.z = v.z > 0.f ? v.z : expm1f(v.z);
                        v.w = v.w > 0.f ? v.w : expm1f(v.w);
                    }
                    *reinterpret_cast<float4*>(&y[(size_t)sg * OUT + o0 + 4 * ti]) = v;
                }
            }
        }
    }
}

// ---------------- final layer: out[orig] = tanh(W6[t] @ h2 + b6[t]) ----------------
__global__ __launch_bounds__(256) void final_kernel(const float* __restrict__ h2,
                                                    const float* __restrict__ W,
                                                    const float* __restrict__ Bv,
                                                    const int* __restrict__ offsets,
                                                    const int* __restrict__ order,
                                                    float* __restrict__ out) {
    const int t = blockIdx.x;
    const int start = offsets[t];
    const int end = offsets[t + 1];
    const int n = (end - start) * 12;
    for (int idx = threadIdx.x; idx < n; idx += 256) {
        int sl = idx / 12;
        int o = idx - sl * 12;
        int s = start + sl;
        const float4* wr = reinterpret_cast<const float4*>(&W[(size_t)(t * 12 + o) * 128]);
        const float4* xr = reinterpret_cast<const float4*>(&h2[(size_t)s * 128]);
        float acc = 0.f;
#pragma unroll 8
        for (int k = 0; k < 32; ++k) {
            float4 a = wr[k];
            float4 b = xr[k];
            acc += a.x * b.x + a.y * b.y + a.z * b.z + a.w * b.w;
        }
        out[(size_t)order[s] * 12 + o] = tanhf(acc + Bv[t * 12 + o]);
    }
}

extern "C" void kernel_launch(void* const* d_in, const int* in_sizes, int n_in,
                              void* d_out, int out_size, void* d_ws, size_t ws_size,
                              hipStream_t stream) {
    const float* obs = (const float*)d_in[0];
    const int* tidx  = (const int*)d_in[1];
    const float* w0  = (const float*)d_in[2];
    const float* b0  = (const float*)d_in[3];
    const float* w2  = (const float*)d_in[4];
    const float* b2  = (const float*)d_in[5];
    const float* w4  = (const float*)d_in[6];
    const float* b4  = (const float*)d_in[7];
    const float* w6  = (const float*)d_in[8];
    const float* b6  = (const float*)d_in[9];
    float* out = (float*)d_out;

    char* ws = (char*)d_ws;
    int* offsets = (int*)ws;                    // 65 ints
    int* order   = (int*)(ws + 1024);           // 2048 ints
    float* h0 = (float*)(ws + 16384);           // 2048*512
    float* h1 = h0 + (size_t)BATCH * 512;       // 2048*256
    float* h2 = h1 + (size_t)BATCH * 256;       // 2048*128

    sort_kernel<<<1, 256, 0, stream>>>(tidx, offsets, order);
    // L0: 48 -> 512, OT=32, KS=4  -> grid 16x64 = 1024 blocks
    layer_kernel<48, 48, 512, 32, 4, true, true>
        <<<dim3(16, NTEACH), 256, 0, stream>>>(obs, w0, b0, offsets, order, h0);
    // L1: 512 -> 256, OT=16, KS=8 -> grid 16x64 = 1024 blocks
    layer_kernel<512, 64, 256, 16, 8, false, true>
        <<<dim3(16, NTEACH), 256, 0, stream>>>(h0, w2, b2, offsets, order, h1);
    // L2: 256 -> 128, OT=16, KS=8 -> grid 8x64 = 512 blocks
    layer_kernel<256, 64, 128, 16, 8, false, true>
        <<<dim3(8, NTEACH), 256, 0, stream>>>(h1, w4, b4, offsets, order, h2);
    final_kernel<<<NTEACH, 256, 0, stream>>>(h2, w6, b6, offsets, order, out);
}

// Round 3
// 48.081 us; speedup vs baseline: 3.8716x; 2.1004x over previous
//
#include <hip/hip_runtime.h>

#define BATCH 2048
#define NTEACH 64

typedef __attribute__((ext_vector_type(8))) short short8;
typedef __attribute__((ext_vector_type(4))) float f32x4;

__device__ __forceinline__ unsigned short f2bf(float f) {
    unsigned u = __float_as_uint(f);
    u += 0x7FFFu + ((u >> 16) & 1u);          // round-to-nearest-even
    return (unsigned short)(u >> 16);
}

__device__ __forceinline__ short8 cvt8(float4 a, float4 b) {
    short8 r;
    r[0] = (short)f2bf(a.x); r[1] = (short)f2bf(a.y);
    r[2] = (short)f2bf(a.z); r[3] = (short)f2bf(a.w);
    r[4] = (short)f2bf(b.x); r[5] = (short)f2bf(b.y);
    r[6] = (short)f2bf(b.z); r[7] = (short)f2bf(b.w);
    return r;
}

// ---------------- sort: bucket samples by teacher ----------------
__global__ __launch_bounds__(256) void sort_kernel(const int* __restrict__ tidx,
                                                   int* __restrict__ offsets,
                                                   int* __restrict__ order) {
    __shared__ int cnt[NTEACH];
    __shared__ int offs[NTEACH + 1];
    __shared__ int cur[NTEACH];
    int tid = threadIdx.x;
    if (tid < NTEACH) cnt[tid] = 0;
    __syncthreads();
    for (int i = tid; i < BATCH; i += 256) atomicAdd(&cnt[tidx[i]], 1);
    __syncthreads();
    if (tid == 0) {
        int a = 0;
        for (int t = 0; t < NTEACH; ++t) { offs[t] = a; a += cnt[t]; }
        offs[NTEACH] = a;
    }
    __syncthreads();
    if (tid < NTEACH) cur[tid] = offs[tid];
    if (tid < NTEACH + 1) offsets[tid] = offs[tid];
    __syncthreads();
    for (int i = tid; i < BATCH; i += 256) {
        int p = atomicAdd(&cur[tidx[i]], 1);
        order[p] = i;
    }
}

// ---------------- gather obs -> sorted bf16, K padded 48->64 ----------------
// 8 threads per row, each writes one short8 (cols c0..c0+7); cols >=48 are zero.
__global__ __launch_bounds__(256) void gather_kernel(const float* __restrict__ obs,
                                                     const int* __restrict__ order,
                                                     unsigned short* __restrict__ obs_s) {
    int gtid = blockIdx.x * 256 + threadIdx.x;   // 64 blocks * 256 = 16384 = 2048*8
    int r = gtid >> 3;
    int c0 = (gtid & 7) * 8;
    short8 v = {0, 0, 0, 0, 0, 0, 0, 0};
    if (c0 < 48) {
        const float* src = obs + (size_t)order[r] * 48 + c0;
        float4 a = *reinterpret_cast<const float4*>(src);
        float4 b = *reinterpret_cast<const float4*>(src + 4);
        v = cvt8(a, b);
    }
    *reinterpret_cast<short8*>(&obs_s[(size_t)r * 64 + c0]) = v;
}

// ---------------- MFMA layer: ys = elu(W @ xs + b), all in sorted space --------
// Block = (64-out tile, teacher); 4 waves each own a 16-out slice.
// B-frags (weights, fp32->bf16) hoisted in registers across the M-loop.
// A/B frags load straight from row-major global memory as 16B — no LDS.
// K = padded K (mult of 32) = row stride of xs; KVALID = true K (W row length).
template <int K, int KVALID, int NOUT>
__global__ __launch_bounds__(256) void layer_mfma(const unsigned short* __restrict__ xs,
                                                  const float* __restrict__ W,
                                                  const float* __restrict__ Bv,
                                                  const int* __restrict__ offsets,
                                                  unsigned short* __restrict__ ys) {
    constexpr int KT = K / 32;
    const int t = blockIdx.y;
    const int start = offsets[t];
    const int end = offsets[t + 1];
    if (start >= end) return;
    const int w = threadIdx.x >> 6;
    const int l = threadIdx.x & 63;
    const int ln = l & 15;            // n within 16-tile (B) / m row (A)
    const int kg = l >> 4;            // k-group: k = kg*8 + j (+ 32*kt)
    const int n0 = blockIdx.x * 64 + w * 16;

    // ---- load + convert B fragments for all K-steps (weights read once) ----
    short8 bfrag[KT];
    const float* wrow = W + ((size_t)t * NOUT + n0 + ln) * KVALID;
#pragma unroll
    for (int kt = 0; kt < KT; ++kt) {
        int kb = kt * 32 + kg * 8;
        short8 f = {0, 0, 0, 0, 0, 0, 0, 0};
        if (kb < KVALID) {
            float4 a = *reinterpret_cast<const float4*>(wrow + kb);
            float4 b = *reinterpret_cast<const float4*>(wrow + kb + 4);
            f = cvt8(a, b);
        }
        bfrag[kt] = f;
    }
    const float bias = Bv[(size_t)t * NOUT + n0 + ln];

    // ---- M loop: one 16-row MFMA tile per iteration ----
    for (int r0 = start; r0 < end; r0 += 16) {
        f32x4 acc = {0.f, 0.f, 0.f, 0.f};
        const unsigned short* xrow = xs + (size_t)(r0 + ln) * K + kg * 8;
#pragma unroll
        for (int kt = 0; kt < KT; ++kt) {
            short8 af = *reinterpret_cast<const short8*>(xrow + kt * 32);
            acc = __builtin_amdgcn_mfma_f32_16x16x32_bf16(af, bfrag[kt], acc, 0, 0, 0);
        }
#pragma unroll
        for (int j = 0; j < 4; ++j) {
            int m = kg * 4 + j;                    // D: col=lane&15, row=(lane>>4)*4+j
            if (r0 + m < end) {
                float v = acc[j] + bias;
                v = v > 0.f ? v : expm1f(v);
                ys[(size_t)(r0 + m) * NOUT + n0 + ln] = f2bf(v);
            }
        }
    }
}

// ---------------- final layer: out[orig] = tanh(W6 @ h2 + b6), fp32 scatter ----
// One block per teacher; 4 waves split M-tiles (N=12 fits one 16-tile).
__global__ __launch_bounds__(256) void final_mfma(const unsigned short* __restrict__ xs,
                                                  const float* __restrict__ W,
                                                  const float* __restrict__ Bv,
                                                  const int* __restrict__ offsets,
                                                  const int* __restrict__ order,
                                                  float* __restrict__ out) {
    constexpr int K = 128, KT = 4, NOUT = 12;
    const int t = blockIdx.x;
    const int start = offsets[t];
    const int end = offsets[t + 1];
    const int w = threadIdx.x >> 6;
    const int l = threadIdx.x & 63;
    const int ln = l & 15;
    const int kg = l >> 4;
    const bool nvalid = ln < NOUT;

    short8 bfrag[KT];
    const float* wrow = W + ((size_t)t * NOUT + (nvalid ? ln : 0)) * K;  // clamp OOB lanes
#pragma unroll
    for (int kt = 0; kt < KT; ++kt) {
        int kb = kt * 32 + kg * 8;
        float4 a = *reinterpret_cast<const float4*>(wrow + kb);
        float4 b = *reinterpret_cast<const float4*>(wrow + kb + 4);
        bfrag[kt] = cvt8(a, b);
    }
    const float bias = nvalid ? Bv[(size_t)t * NOUT + ln] : 0.f;

    for (int mt = w;; mt += 4) {
        int r0 = start + mt * 16;
        if (r0 >= end) break;
        f32x4 acc = {0.f, 0.f, 0.f, 0.f};
        const unsigned short* xrow = xs + (size_t)(r0 + ln) * K + kg * 8;
#pragma unroll
        for (int kt = 0; kt < KT; ++kt) {
            short8 af = *reinterpret_cast<const short8*>(xrow + kt * 32);
            acc = __builtin_amdgcn_mfma_f32_16x16x32_bf16(af, bfrag[kt], acc, 0, 0, 0);
        }
        if (nvalid) {
#pragma unroll
            for (int j = 0; j < 4; ++j) {
                int m = kg * 4 + j;
                if (r0 + m < end)
                    out[(size_t)order[r0 + m] * NOUT + ln] = tanhf(acc[j] + bias);
            }
        }
    }
}

extern "C" void kernel_launch(void* const* d_in, const int* in_sizes, int n_in,
                              void* d_out, int out_size, void* d_ws, size_t ws_size,
                              hipStream_t stream) {
    const float* obs = (const float*)d_in[0];
    const int* tidx  = (const int*)d_in[1];
    const float* w0  = (const float*)d_in[2];
    const float* b0  = (const float*)d_in[3];
    const float* w2  = (const float*)d_in[4];
    const float* b2  = (const float*)d_in[5];
    const float* w4  = (const float*)d_in[6];
    const float* b4  = (const float*)d_in[7];
    const float* w6  = (const float*)d_in[8];
    const float* b6  = (const float*)d_in[9];
    float* out = (float*)d_out;

    // workspace layout (bf16 activations in sorted space, +16 rows slack for
    // A-fragment overread on the last teacher's tail — rows never stored)
    const int ROWS = BATCH + 16;
    char* ws = (char*)d_ws;
    int* offsets = (int*)ws;                                   // 65 ints
    int* order   = (int*)(ws + 1024);                          // 2048 ints
    unsigned short* obs_s = (unsigned short*)(ws + 16384);     // ROWS*64
    unsigned short* h0 = obs_s + (size_t)ROWS * 64;            // ROWS*512
    unsigned short* h1 = h0 + (size_t)ROWS * 512;              // ROWS*256
    unsigned short* h2 = h1 + (size_t)ROWS * 256;              // ROWS*128

    sort_kernel<<<1, 256, 0, stream>>>(tidx, offsets, order);
    gather_kernel<<<64, 256, 0, stream>>>(obs, order, obs_s);
    layer_mfma<64, 48, 512><<<dim3(8, NTEACH), 256, 0, stream>>>(obs_s, w0, b0, offsets, h0);
    layer_mfma<512, 512, 256><<<dim3(4, NTEACH), 256, 0, stream>>>(h0, w2, b2, offsets, h1);
    layer_mfma<256, 256, 128><<<dim3(2, NTEACH), 256, 0, stream>>>(h1, w4, b4, offsets, h2);
    final_mfma<<<NTEACH, 256, 0, stream>>>(h2, w6, b6, offsets, order, out);
}

// Round 4
// 39.362 us; speedup vs baseline: 4.7292x; 1.2215x over previous
//
#include <hip/hip_runtime.h>

#define BATCH 2048
#define NTEACH 64

typedef __attribute__((ext_vector_type(8))) short short8;
typedef __attribute__((ext_vector_type(4))) float f32x4;

__device__ __forceinline__ unsigned short f2bf(float f) {
    unsigned u = __float_as_uint(f);
    u += 0x7FFFu + ((u >> 16) & 1u);          // round-to-nearest-even
    return (unsigned short)(u >> 16);
}

__device__ __forceinline__ short8 cvt8(float4 a, float4 b) {
    short8 r;
    r[0] = (short)f2bf(a.x); r[1] = (short)f2bf(a.y);
    r[2] = (short)f2bf(a.z); r[3] = (short)f2bf(a.w);
    r[4] = (short)f2bf(b.x); r[5] = (short)f2bf(b.y);
    r[6] = (short)f2bf(b.z); r[7] = (short)f2bf(b.w);
    return r;
}

// ---------------- sort: bucket samples by teacher ----------------
__global__ __launch_bounds__(1024) void sort_kernel(const int* __restrict__ tidx,
                                                    int* __restrict__ offsets,
                                                    int* __restrict__ order) {
    __shared__ int cnt[NTEACH];
    __shared__ int offs[NTEACH + 1];
    __shared__ int cur[NTEACH];
    int tid = threadIdx.x;
    if (tid < NTEACH) cnt[tid] = 0;
    __syncthreads();
    for (int i = tid; i < BATCH; i += 1024) atomicAdd(&cnt[tidx[i]], 1);
    __syncthreads();
    if (tid == 0) {
        int a = 0;
        for (int t = 0; t < NTEACH; ++t) { offs[t] = a; a += cnt[t]; }
        offs[NTEACH] = a;
    }
    __syncthreads();
    if (tid < NTEACH) cur[tid] = offs[tid];
    if (tid < NTEACH + 1) offsets[tid] = offs[tid];
    __syncthreads();
    for (int i = tid; i < BATCH; i += 1024) {
        int p = atomicAdd(&cur[tidx[i]], 1);
        order[p] = i;
    }
}

// ---------------- MFMA layer (sorted space), wave split over K/N/M ----------
// Block = (16*NSPLIT out tile, teacher); 4 waves = KSPLIT x NSPLIT x MSPLIT.
// KSPLIT>1: waves own K-slices, partials reduced through LDS (requires MSPLIT==1
// so barrier counts match). GATHER: A rows gathered from fp32 obs via order[]
// and converted in-register (stride KVALID fp32); else A rows are bf16, stride K.
template <int K, int KVALID, int NOUT, int KSPLIT, int NSPLIT, int MSPLIT,
          bool GATHER, bool IS_ELU>
__global__ __launch_bounds__(256) void layer_mfma(const void* __restrict__ xin,
                                                  const float* __restrict__ W,
                                                  const float* __restrict__ Bv,
                                                  const int* __restrict__ offsets,
                                                  const int* __restrict__ order,
                                                  unsigned short* __restrict__ ys) {
    constexpr int KSL = K / KSPLIT;     // K per wave
    constexpr int KTW = KSL / 32;       // MFMA K-steps per wave
    static_assert(KSL % 32 == 0, "K slice");
    static_assert(KSPLIT * NSPLIT * MSPLIT == 4, "4 waves");
    static_assert(KSPLIT == 1 || MSPLIT == 1, "barrier uniformity");

    __shared__ f32x4 red[4][64];

    const int t = blockIdx.y;
    const int start = offsets[t];
    const int end = offsets[t + 1];
    if (start >= end) return;
    const int wid = threadIdx.x >> 6;
    const int l = threadIdx.x & 63;
    const int ln = l & 15;              // B col / D col
    const int kg = l >> 4;              // k-group
    const int kq = wid % KSPLIT;
    const int nq = (wid / KSPLIT) % NSPLIT;
    const int mq = wid / (KSPLIT * NSPLIT);
    const int n0 = blockIdx.x * (16 * NSPLIT) + nq * 16;
    const int kbase = kq * KSL;

    // ---- B fragments: weight slice, fp32 -> bf16 in-register, read once ----
    short8 bfrag[KTW];
    const float* wrow = W + ((size_t)t * NOUT + n0 + ln) * KVALID + kbase;
#pragma unroll
    for (int kt = 0; kt < KTW; ++kt) {
        int kb = kt * 32 + kg * 8;
        short8 f = {0, 0, 0, 0, 0, 0, 0, 0};
        if (kbase + kb < KVALID) {
            float4 a = *reinterpret_cast<const float4*>(wrow + kb);
            float4 b = *reinterpret_cast<const float4*>(wrow + kb + 4);
            f = cvt8(a, b);
        }
        bfrag[kt] = f;
    }
    const float bias = Bv[(size_t)t * NOUT + n0 + ln];

    for (int r0 = start + mq * 16; r0 < end; r0 += 16 * MSPLIT) {
        f32x4 acc = {0.f, 0.f, 0.f, 0.f};
        if (GATHER) {
            int rr = (r0 + ln < end) ? order[r0 + ln] : order[start];
            const float* xr = (const float*)xin + (size_t)rr * KVALID + kbase;
#pragma unroll
            for (int kt = 0; kt < KTW; ++kt) {
                int kb = kt * 32 + kg * 8;
                short8 af = {0, 0, 0, 0, 0, 0, 0, 0};
                if (kbase + kb < KVALID) {
                    float4 a = *reinterpret_cast<const float4*>(xr + kb);
                    float4 b = *reinterpret_cast<const float4*>(xr + kb + 4);
                    af = cvt8(a, b);
                }
                acc = __builtin_amdgcn_mfma_f32_16x16x32_bf16(af, bfrag[kt], acc, 0, 0, 0);
            }
        } else {
            const unsigned short* xr =
                (const unsigned short*)xin + (size_t)(r0 + ln) * K + kbase + kg * 8;
#pragma unroll
            for (int kt = 0; kt < KTW; ++kt) {
                short8 af = *reinterpret_cast<const short8*>(xr + kt * 32);
                acc = __builtin_amdgcn_mfma_f32_16x16x32_bf16(af, bfrag[kt], acc, 0, 0, 0);
            }
        }
        if (KSPLIT > 1) {
            __syncthreads();
            if (kq > 0) red[wid][l] = acc;
            __syncthreads();
            if (kq == 0) {
#pragma unroll
                for (int s = 1; s < KSPLIT; ++s) {
                    f32x4 r = red[wid + s][l];
                    acc[0] += r[0]; acc[1] += r[1]; acc[2] += r[2]; acc[3] += r[3];
                }
            }
        }
        if (kq == 0) {
#pragma unroll
            for (int j = 0; j < 4; ++j) {
                int m = kg * 4 + j;                 // D: col=lane&15, row=(lane>>4)*4+j
                if (r0 + m < end) {
                    float v = acc[j] + bias;
                    if (IS_ELU) v = v > 0.f ? v : expm1f(v);
                    ys[(size_t)(r0 + m) * NOUT + n0 + ln] = f2bf(v);
                }
            }
        }
    }
}

// ---------------- final layer: out[orig] = tanh(W6 @ h2 + b6), fp32 scatter ----
__global__ __launch_bounds__(256) void final_mfma(const unsigned short* __restrict__ xs,
                                                  const float* __restrict__ W,
                                                  const float* __restrict__ Bv,
                                                  const int* __restrict__ offsets,
                                                  const int* __restrict__ order,
                                                  float* __restrict__ out) {
    constexpr int K = 128, KT = 4, NOUT = 12;
    const int t = blockIdx.x;
    const int start = offsets[t];
    const int end = offsets[t + 1];
    const int w = threadIdx.x >> 6;
    const int l = threadIdx.x & 63;
    const int ln = l & 15;
    const int kg = l >> 4;
    const bool nvalid = ln < NOUT;

    short8 bfrag[KT];
    const float* wrow = W + ((size_t)t * NOUT + (nvalid ? ln : 0)) * K;
#pragma unroll
    for (int kt = 0; kt < KT; ++kt) {
        int kb = kt * 32 + kg * 8;
        float4 a = *reinterpret_cast<const float4*>(wrow + kb);
        float4 b = *reinterpret_cast<const float4*>(wrow + kb + 4);
        bfrag[kt] = cvt8(a, b);
    }
    const float bias = nvalid ? Bv[(size_t)t * NOUT + ln] : 0.f;

    for (int mt = w;; mt += 4) {
        int r0 = start + mt * 16;
        if (r0 >= end) break;
        f32x4 acc = {0.f, 0.f, 0.f, 0.f};
        const unsigned short* xrow = xs + (size_t)(r0 + ln) * K + kg * 8;
#pragma unroll
        for (int kt = 0; kt < KT; ++kt) {
            short8 af = *reinterpret_cast<const short8*>(xrow + kt * 32);
            acc = __builtin_amdgcn_mfma_f32_16x16x32_bf16(af, bfrag[kt], acc, 0, 0, 0);
        }
        if (nvalid) {
#pragma unroll
            for (int j = 0; j < 4; ++j) {
                int m = kg * 4 + j;
                if (r0 + m < end)
                    out[(size_t)order[r0 + m] * NOUT + ln] = tanhf(acc[j] + bias);
            }
        }
    }
}

extern "C" void kernel_launch(void* const* d_in, const int* in_sizes, int n_in,
                              void* d_out, int out_size, void* d_ws, size_t ws_size,
                              hipStream_t stream) {
    const float* obs = (const float*)d_in[0];
    const int* tidx  = (const int*)d_in[1];
    const float* w0  = (const float*)d_in[2];
    const float* b0  = (const float*)d_in[3];
    const float* w2  = (const float*)d_in[4];
    const float* b2  = (const float*)d_in[5];
    const float* w4  = (const float*)d_in[6];
    const float* b4  = (const float*)d_in[7];
    const float* w6  = (const float*)d_in[8];
    const float* b6  = (const float*)d_in[9];
    float* out = (float*)d_out;

    // bf16 activations in sorted space; +64 rows slack so A-fragment tile
    // overreads on the last teacher stay in-bounds (those rows are finite
    // garbage and their D rows are never stored).
    const int ROWS = BATCH + 64;
    char* ws = (char*)d_ws;
    int* offsets = (int*)ws;                              // 65 ints
    int* order   = (int*)(ws + 1024);                     // 2048 ints
    unsigned short* h0 = (unsigned short*)(ws + 16384);   // ROWS*512
    unsigned short* h1 = h0 + (size_t)ROWS * 512;         // ROWS*256
    unsigned short* h2 = h1 + (size_t)ROWS * 256;         // ROWS*128

    sort_kernel<<<1, 1024, 0, stream>>>(tidx, offsets, order);
    // L0: 48->512 (K padded to 64), gather fused; waves = N2 x M2. 1024 blocks.
    layer_mfma<64, 48, 512, 1, 2, 2, true, true>
        <<<dim3(16, NTEACH), 256, 0, stream>>>(obs, w0, b0, offsets, order, h0);
    // L1: 512->256; waves = K4. 1024 blocks.
    layer_mfma<512, 512, 256, 4, 1, 1, false, true>
        <<<dim3(16, NTEACH), 256, 0, stream>>>(h0, w2, b2, offsets, order, h1);
    // L2: 256->128; waves = K4. 512 blocks.
    layer_mfma<256, 256, 128, 4, 1, 1, false, true>
        <<<dim3(8, NTEACH), 256, 0, stream>>>(h1, w4, b4, offsets, order, h2);
    final_mfma<<<NTEACH, 256, 0, stream>>>(h2, w6, b6, offsets, order, out);
}